// Round 7
// baseline (8287.634 us; speedup 1.0000x reference)
//
#include <hip/hip_runtime.h>
#include <hip/hip_fp16.h>

typedef _Float16 half8 __attribute__((ext_vector_type(8)));
typedef float    float4_ __attribute__((ext_vector_type(4)));

#define TSTEPS 512
#define NA 64
#define NB 128
#define NC 8
#define FSTRIDE 32                // ints per flag slot = 128 B (own cache line)

// workspace layout (bytes) — IDENTICAL to the proven R1/R4 layout
#define FLA_OFF   0               // 64 flags  x 128 B
#define FLB_OFF   8192            // 128 flags x 128 B
#define FLC_OFF   24576           // 8 flags   x 128 B
#define H1_OFF    32768
#define H1_PHASE  262144          // 1024 cols x 128 batch x 2B, fragment-major
#define H2_OFF    (H1_OFF + 2 * H1_PHASE)
#define X_OFF     (H2_OFF + 2 * H1_PHASE)
#define X_TSTRIDE 16384           // 64 cols x 128 batch x 2B per step
#define ZERO_BYTES X_OFF          // flags + H1 + H2 zeroed each call

// fast activations: v_rcp_f32 + v_exp (R4-proven numerics-neutral)
__device__ __forceinline__ float fastrcp(float x) {
    float r; asm("v_rcp_f32 %0, %1" : "=v"(r) : "v"(x)); return r;
}
__device__ __forceinline__ float sigf(float x)  { return fastrcp(1.0f + __expf(-x)); }
__device__ __forceinline__ float tanh_(float x) { return 1.0f - 2.0f * fastrcp(1.0f + __expf(2.0f * x)); }

__device__ __forceinline__ half8 zero8() {
    half8 z;
#pragma unroll
    for (int j = 0; j < 8; ++j) z[j] = (_Float16)0.0f;
    return z;
}

__device__ __forceinline__ half8 wfrag_load(const float* Wa, int lda,
                                            const float* Wb, int ldb,
                                            int split, int row, int k0) {
    const float* s = (k0 < split) ? (Wa + (size_t)row * lda + k0)
                                  : (Wb + (size_t)row * ldb + (k0 - split));
    float4_ lo = *(const float4_*)s;
    float4_ hi = *(const float4_*)(s + 4);
    half8 r;
    r[0] = (_Float16)lo[0]; r[1] = (_Float16)lo[1];
    r[2] = (_Float16)lo[2]; r[3] = (_Float16)lo[3];
    r[4] = (_Float16)hi[0]; r[5] = (_Float16)hi[1];
    r[6] = (_Float16)hi[2]; r[7] = (_Float16)hi[3];
    return r;
}

// ---- coherence recipe (R7): producers write through (sc0 sc1) BEFORE flag;
// consumers observe flag, execute an agent-scope ACQUIRE fence (compiler emits
// the proper L1/L2 invalidate sequence for gfx950), then use PLAIN cacheable
// loads. Activation lines are then fetched from the coherence point once per
// XCD and served at L2 latency, instead of per-load sc1 fabric round-trips. ----

// plain 16B load (cacheable, L1/L2). Consumer must pass the value through a
// VMWAIT* fence below before use (compiler inserts no waitcnt for asm loads).
__device__ __forceinline__ half8 ldg_16(const void* p) {
    half8 r;
    asm volatile("global_load_dwordx4 %0, %1, off" : "=v"(r) : "v"(p));
    return r;
}

#define VMWAIT8(A) asm volatile("s_waitcnt vmcnt(0)" : \
    "+v"((A)[0]), "+v"((A)[1]), "+v"((A)[2]), "+v"((A)[3]), \
    "+v"((A)[4]), "+v"((A)[5]), "+v"((A)[6]), "+v"((A)[7]) :: "memory")

#define VMWAIT9_N(A, NS) asm volatile("s_waitcnt vmcnt(" NS ")" : \
    "+v"((A)[0]), "+v"((A)[1]), "+v"((A)[2]), "+v"((A)[3]), "+v"((A)[4]), \
    "+v"((A)[5]), "+v"((A)[6]), "+v"((A)[7]), "+v"((A)[8]) :: "memory")
#define VMWAIT8_N(A, NS) asm volatile("s_waitcnt vmcnt(" NS ")" : \
    "+v"((A)[0]), "+v"((A)[1]), "+v"((A)[2]), "+v"((A)[3]), \
    "+v"((A)[4]), "+v"((A)[5]), "+v"((A)[6]), "+v"((A)[7]) :: "memory")

// 16B write-through store (sc0 sc1): full-line-coalescable publish store.
__device__ __forceinline__ void stg_coh_16(void* p, float4_ v) {
    asm volatile("global_store_dwordx4 %0, %1, off sc0 sc1" :: "v"(p), "v"(v) : "memory");
}

__device__ __forceinline__ void stg_coh_int(void* p, int v) {
    asm volatile("global_store_dword %0, %1, off sc0 sc1" :: "v"(p), "v"(v) : "memory");
}

// producer-side ordering: my write-through stores acked (vmcnt 0), then block
// barrier, then (thread 0) flag store.
__device__ __forceinline__ void publish(int* fbase, int idx, int v) {
    asm volatile("s_waitcnt vmcnt(0)" ::: "memory");
    __syncthreads();
    if (threadIdx.x == 0) stg_coh_int(fbase + idx * FSTRIDE, v);
}

__device__ __forceinline__ int ld_flag(const int* f, int idx) {
    return __hip_atomic_load(f + idx * FSTRIDE, __ATOMIC_RELAXED,
                             __HIP_MEMORY_SCOPE_AGENT);
}

// consumer-side acquire: invalidate stale L1/L2 lines so plain loads refill
// from the coherence point (which has the producer's write-through data).
__device__ __forceinline__ void fence_acq() {
    __builtin_amdgcn_fence(__ATOMIC_ACQUIRE, "agent");
}

// A-group: need all fA >= t (h1[t-1] ready) and all fB >= t-1 (phase free)
__device__ __forceinline__ void waitA(const int* fA, const int* fB, int t) {
    if (threadIdx.x < 64) {
        const int lane = threadIdx.x;
        for (;;) {
            int a  = ld_flag(fA, lane);
            int b0 = ld_flag(fB, lane);
            int b1 = ld_flag(fB, 64 + lane);
            if (__all((a >= t) && (b0 >= t - 1) && (b1 >= t - 1))) break;
            __builtin_amdgcn_s_sleep(1);
        }
    }
    __syncthreads();
    fence_acq();
}

// B-group: fA >= t+1 (h1[t]), fB >= t (h2[t-1]), fC >= t-1 (phase free)
__device__ __forceinline__ void waitB(const int* fA, const int* fB, const int* fC, int t) {
    if (threadIdx.x < 64) {
        const int lane = threadIdx.x;
        for (;;) {
            int a  = ld_flag(fA, lane);
            int b0 = ld_flag(fB, lane);
            int b1 = ld_flag(fB, 64 + lane);
            int c  = ld_flag(fC, lane & 7);
            if (__all((a >= t + 1) && (b0 >= t) && (b1 >= t) && (c >= t - 1))) break;
            __builtin_amdgcn_s_sleep(1);
        }
    }
    __syncthreads();
    fence_acq();
}

// C-group: fB >= t+1 (h2[t] ready)
__device__ __forceinline__ void waitC(const int* fB, int t) {
    if (threadIdx.x < 64) {
        const int lane = threadIdx.x;
        for (;;) {
            int b0 = ld_flag(fB, lane);
            int b1 = ld_flag(fB, 64 + lane);
            if (__all((b0 >= t + 1) && (b1 >= t + 1))) break;
            __builtin_amdgcn_s_sleep(1);
        }
    }
    __syncthreads();
    fence_acq();
}

// staging-image chunk swizzle (R3/R4-proven: conflict-free, bijective)
__device__ __forceinline__ int swz(int u) {
    return u ^ (((u >> 3) ^ (u >> 7)) & 7);
}

// Convert input [128 b][512 t][64 i] fp32 -> fragment-major fp16 X[t][kt][quad][b][j]
extern "C" __global__ void prep_x(const float* __restrict__ in, char* __restrict__ ws) {
    const int t = blockIdx.x;
    char* X = ws + X_OFF + (size_t)t * X_TSTRIDE;
    for (int idx = threadIdx.x; idx < 8192; idx += 256) {
        int kt = idx >> 12, rem = idx & 4095;
        int quad = rem >> 10, rem2 = rem & 1023;
        int b = rem2 >> 3, j = rem2 & 7;
        int i = kt * 32 + quad * 8 + j;
        float v = in[(size_t)b * 32768 + (size_t)t * 64 + i];
        *(_Float16*)(X + (size_t)idx * 2) = (_Float16)v;
    }
}

extern "C" __global__ __launch_bounds__(256, 1)
void lstm_persistent(const float* __restrict__ Wih1, const float* __restrict__ Whh1,
                     const float* __restrict__ bih1, const float* __restrict__ bhh1,
                     const float* __restrict__ Wih2, const float* __restrict__ Whh2,
                     const float* __restrict__ bih2, const float* __restrict__ bhh2,
                     const float* __restrict__ Wout, const float* __restrict__ bout,
                     char* __restrict__ ws, float* __restrict__ out) {
    const int tid = threadIdx.x;
    const int w = tid >> 6, lane = tid & 63;
    const int quad = lane >> 4, cl = lane & 15;
    const int laneoff = quad * 2048 + cl * 16;
    int* fA = (int*)(ws + FLA_OFF);
    int* fB = (int*)(ws + FLB_OFF);
    int* fC = (int*)(ws + FLC_OFF);
    char* H1 = ws + H1_OFF;
    char* H2 = ws + H2_OFF;
    char* X  = ws + X_OFF;
    const int blk = blockIdx.x;
    __shared__ float redbuf[8192];                 // 32 KiB reduction scratch
    __shared__ __align__(16) unsigned short stg[2048];  // 4 KiB staging image

    if (blk < NA) {
        // ---------- layer-1: h1 cols [c0,c0+16), K = 1088 (34 k-tiles), waves split K
        const int c0 = blk * 16;
        const int kbase = w * 9;
        half8 wfr[4][9];
#pragma unroll
        for (int nt = 0; nt < 4; ++nt) {
            int row = nt * 1024 + c0 + cl;
#pragma unroll
            for (int kk = 0; kk < 9; ++kk) {
                int ktg = kbase + kk;
                if (ktg < 34) wfr[nt][kk] = wfrag_load(Wih1, 64, Whh1, 1024, 64, row, ktg * 32 + quad * 8);
                else          wfr[nt][kk] = zero8();
            }
        }
        float ba[4];
#pragma unroll
        for (int g = 0; g < 4; ++g) ba[g] = bih1[g * 1024 + c0 + cl] + bhh1[g * 1024 + c0 + cl];
        float cst[2][4];
#pragma unroll
        for (int mi = 0; mi < 2; ++mi)
#pragma unroll
            for (int r = 0; r < 4; ++r) cst[mi][r] = 0.0f;

        for (int t = 0; t < TSTEPS; ++t) {
            waitA(fA, fB, t);

            const char* xb  = X + (size_t)t * X_TSTRIDE;
            const char* h1r = H1 + (((t & 1) ^ 1) ? H1_PHASE : 0);
            char*       h1w = H1 + ((t & 1) ? H1_PHASE : 0);
            const char* kb[9];
#pragma unroll
            for (int kk = 0; kk < 9; ++kk) {
                int ktg = kbase + kk; if (ktg > 33) ktg = 33;
                kb[kk] = (ktg < 2) ? (xb + ktg * 8192) : (h1r + (ktg - 2) * 8192);
            }
            // 3-buffer, distance-2 prefetch with counted waits
            half8 af[3][9];
#pragma unroll
            for (int g = 0; g < 2; ++g)
#pragma unroll
                for (int kk = 0; kk < 9; ++kk)
                    af[g][kk] = ldg_16(kb[kk] + laneoff + g * 256);
            float4_ acc[8][4];
#pragma unroll
            for (int mt = 0; mt < 8; ++mt)
#pragma unroll
                for (int nt = 0; nt < 4; ++nt) acc[mt][nt] = (float4_){0.f, 0.f, 0.f, 0.f};
#pragma unroll
            for (int mt = 0; mt < 8; ++mt) {
                const int cur = mt % 3;
                if (mt < 7) { VMWAIT9_N(af[cur], "9"); }
                else        { VMWAIT9_N(af[cur], "0"); }
                if (mt < 6) {
                    const int nx = (mt + 2) % 3;
#pragma unroll
                    for (int kk = 0; kk < 9; ++kk)
                        af[nx][kk] = ldg_16(kb[kk] + laneoff + (mt + 2) * 256);
                }
#pragma unroll
                for (int kk = 0; kk < 9; ++kk)
#pragma unroll
                    for (int nt = 0; nt < 4; ++nt)
                        acc[mt][nt] = __builtin_amdgcn_mfma_f32_16x16x32_f16(
                            af[cur][kk], wfr[nt][kk], acc[mt][nt], 0, 0, 0);
            }
#pragma unroll
            for (int r = 0; r < 4; ++r) {
                if (w != r) {
#pragma unroll
                    for (int mi = 0; mi < 2; ++mi)
#pragma unroll
                        for (int nt = 0; nt < 4; ++nt)
                            *(float4_*)&redbuf[(((w * 2 + mi) * 4 + nt) * 64 + lane) * 4] = acc[2 * r + mi][nt];
                }
                __syncthreads();
                if (w == r) {
#pragma unroll
                    for (int wo = 0; wo < 4; ++wo) if (wo != r) {
#pragma unroll
                        for (int mi = 0; mi < 2; ++mi)
#pragma unroll
                            for (int nt = 0; nt < 4; ++nt)
                                acc[2 * r + mi][nt] += *(const float4_*)&redbuf[(((wo * 2 + mi) * 4 + nt) * 64 + lane) * 4];
                    }
                }
                __syncthreads();
            }
            float4_ mine[2][4];
#pragma unroll
            for (int r = 0; r < 4; ++r) if (w == r) {
#pragma unroll
                for (int mi = 0; mi < 2; ++mi)
#pragma unroll
                    for (int nt = 0; nt < 4; ++nt) mine[mi][nt] = acc[2 * r + mi][nt];
            }
            // nonlinearity -> swizzled staging image of the fragment-major dest
#pragma unroll
            for (int mi = 0; mi < 2; ++mi) {
#pragma unroll
                for (int r = 0; r < 4; ++r) {
                    float iv = mine[mi][0][r] + ba[0];
                    float fv = mine[mi][1][r] + ba[1];
                    float gv = mine[mi][2][r] + ba[2];
                    float ov = mine[mi][3][r] + ba[3];
                    float c = sigf(fv) * cst[mi][r] + sigf(iv) * tanh_(gv);
                    float h = sigf(ov) * tanh_(c);
                    cst[mi][r] = c;
                    int m = (2 * w + mi) * 16 + quad * 4 + r;
                    int u = ((cl >> 3) << 7) + m;
                    union { _Float16 hh; unsigned short us; } uu;
                    uu.hh = (_Float16)h;
                    stg[swz(u) * 8 + (cl & 7)] = uu.us;
                }
            }
            __syncthreads();
            // coalesced publish: one 16B full-line-combinable store per thread
            {
                const int g = tid >> 7, b = tid & 127;
                int u = (g << 7) + b;
                float4_ v = *(const float4_*)(stg + swz(u) * 8);
                char* dst = h1w + ((c0 >> 5) << 13) + ((((c0 >> 3) + g) & 3) << 11) + (b << 4);
                stg_coh_16(dst, v);
            }
            publish(fA, blk, t + 1);
        }
    } else if (blk < NA + NB) {
        // ---------- layer-2: h2 cols [c0,c0+8), K = 2048 (64 k-tiles), waves split K
        const int bb = blk - NA;
        const int c0 = bb * 8;
        const int kbase = w * 16;
        const int colB = c0 + (cl & 7);
        const int row0 = (cl < 8) ? colB : (1024 + colB);
        const int row1 = (cl < 8) ? (2048 + colB) : (3072 + colB);
        half8 wfr[2][16];
#pragma unroll
        for (int kk = 0; kk < 16; ++kk) {
            int k0 = (kbase + kk) * 32 + quad * 8;
            wfr[0][kk] = wfrag_load(Wih2, 1024, Whh2, 1024, 1024, row0, k0);
            wfr[1][kk] = wfrag_load(Wih2, 1024, Whh2, 1024, 1024, row1, k0);
        }
        const float bi = bih2[colB] + bhh2[colB];
        const float bf = bih2[1024 + colB] + bhh2[1024 + colB];
        const float bg = bih2[2048 + colB] + bhh2[2048 + colB];
        const float bo = bih2[3072 + colB] + bhh2[3072 + colB];
        float cst[2][4];
#pragma unroll
        for (int mi = 0; mi < 2; ++mi)
#pragma unroll
            for (int r = 0; r < 4; ++r) cst[mi][r] = 0.0f;
        const bool lolane = (cl & 8) == 0;

        for (int t = 0; t < TSTEPS; ++t) {
            waitB(fA, fB, fC, t);

            const char* h1c = H1 + ((t & 1) ? H1_PHASE : 0);
            const char* h2r = H2 + (((t & 1) ^ 1) ? H1_PHASE : 0);
            char*       h2w = H2 + ((t & 1) ? H1_PHASE : 0);
            const char* kb[16];
#pragma unroll
            for (int kk = 0; kk < 16; ++kk) {
                int ktg = kbase + kk;
                kb[kk] = (ktg < 32) ? (h1c + ktg * 8192) : (h2r + (ktg - 32) * 8192);
            }
            float4_ acc[8][2];
#pragma unroll
            for (int mt = 0; mt < 8; ++mt) {
                acc[mt][0] = (float4_){0.f, 0.f, 0.f, 0.f};
                acc[mt][1] = (float4_){0.f, 0.f, 0.f, 0.f};
            }
            // 4-buffer, sub-groups of 8 loads, distance-3 prefetch, counted waits.
            half8 af[4][8];
#pragma unroll
            for (int s = 0; s < 3; ++s)
#pragma unroll
                for (int k2 = 0; k2 < 8; ++k2)
                    af[s][k2] = ldg_16(kb[(s & 1) * 8 + k2] + laneoff + (s >> 1) * 256);
#pragma unroll
            for (int s = 0; s < 16; ++s) {
                const int cur = s & 3;
                if (s < 14)      { VMWAIT8_N(af[cur], "16"); }
                else if (s == 14){ VMWAIT8_N(af[cur], "8");  }
                else             { VMWAIT8_N(af[cur], "0");  }
                if (s < 13) {
                    const int nx = (s + 3) & 3;
#pragma unroll
                    for (int k2 = 0; k2 < 8; ++k2)
                        af[nx][k2] = ldg_16(kb[((s + 3) & 1) * 8 + k2] + laneoff + ((s + 3) >> 1) * 256);
                }
                const int mt = s >> 1, hb = (s & 1) * 8;
#pragma unroll
                for (int k2 = 0; k2 < 8; ++k2) {
                    acc[mt][0] = __builtin_amdgcn_mfma_f32_16x16x32_f16(af[cur][k2], wfr[0][hb + k2], acc[mt][0], 0, 0, 0);
                    acc[mt][1] = __builtin_amdgcn_mfma_f32_16x16x32_f16(af[cur][k2], wfr[1][hb + k2], acc[mt][1], 0, 0, 0);
                }
            }
#pragma unroll
            for (int r = 0; r < 4; ++r) {
                if (w != r) {
#pragma unroll
                    for (int mi = 0; mi < 2; ++mi)
#pragma unroll
                        for (int nt = 0; nt < 2; ++nt)
                            *(float4_*)&redbuf[(((w * 2 + mi) * 2 + nt) * 64 + lane) * 4] = acc[2 * r + mi][nt];
                }
                __syncthreads();
                if (w == r) {
#pragma unroll
                    for (int wo = 0; wo < 4; ++wo) if (wo != r) {
#pragma unroll
                        for (int mi = 0; mi < 2; ++mi)
#pragma unroll
                            for (int nt = 0; nt < 2; ++nt)
                                acc[2 * r + mi][nt] += *(const float4_*)&redbuf[(((wo * 2 + mi) * 2 + nt) * 64 + lane) * 4];
                    }
                }
                __syncthreads();
            }
            float4_ mine[2][2];
#pragma unroll
            for (int r = 0; r < 4; ++r) if (w == r) {
#pragma unroll
                for (int mi = 0; mi < 2; ++mi) {
                    mine[mi][0] = acc[2 * r + mi][0];
                    mine[mi][1] = acc[2 * r + mi][1];
                }
            }
#pragma unroll
            for (int mi = 0; mi < 2; ++mi) {
#pragma unroll
                for (int r = 0; r < 4; ++r) {
                    float d0 = mine[mi][0][r], d1 = mine[mi][1][r];
                    float s0 = __shfl_xor(d0, 8, 64);
                    float s1 = __shfl_xor(d1, 8, 64);
                    float iv = (lolane ? d0 : s0) + bi;
                    float fv = (lolane ? s0 : d0) + bf;
                    float gv = (lolane ? d1 : s1) + bg;
                    float ov = (lolane ? s1 : d1) + bo;
                    float c = sigf(fv) * cst[mi][r] + sigf(iv) * tanh_(gv);
                    float h = sigf(ov) * tanh_(c);
                    cst[mi][r] = c;
                    if (lolane) {
                        int m = (2 * w + mi) * 16 + quad * 4 + r;
                        union { _Float16 hh; unsigned short us; } uu;
                        uu.hh = (_Float16)h;
                        stg[swz(m) * 8 + (cl & 7)] = uu.us;
                    }
                }
            }
            __syncthreads();
            if (tid < 128) {
                const int b = tid;
                float4_ v = *(const float4_*)(stg + swz(b) * 8);
                char* dst = h2w + ((c0 >> 5) << 13) + (((c0 >> 3) & 3) << 11) + (b << 4);
                stg_coh_16(dst, v);
            }
            publish(fB, bb, t + 1);
        }
    } else {
        // ---------- output: batch tile cb, y = h2 @ Wout^T + bout, K = 1024
        const int cb = blk - NA - NB;
        const int kbase = w * 8;
        half8 wfr[4][8];
#pragma unroll
        for (int nt = 0; nt < 4; ++nt) {
            int row = nt * 16 + cl;
#pragma unroll
            for (int kk = 0; kk < 8; ++kk)
                wfr[nt][kk] = wfrag_load(Wout, 1024, Wout, 1024, 1 << 30, row, (kbase + kk) * 32 + quad * 8);
        }
        const float bo_ = bout[w * 16 + cl];

        for (int t = 0; t < TSTEPS; ++t) {
            waitC(fB, t);
            const char* h2c = H2 + ((t & 1) ? H1_PHASE : 0);
            float4_ acc[4];
#pragma unroll
            for (int nt = 0; nt < 4; ++nt) acc[nt] = (float4_){0.f, 0.f, 0.f, 0.f};
            half8 af[8];
#pragma unroll
            for (int kk = 0; kk < 8; ++kk)
                af[kk] = ldg_16(h2c + (kbase + kk) * 8192 + laneoff + cb * 256);
            VMWAIT8(af);
#pragma unroll
            for (int kk = 0; kk < 8; ++kk)
#pragma unroll
                for (int nt = 0; nt < 4; ++nt)
                    acc[nt] = __builtin_amdgcn_mfma_f32_16x16x32_f16(af[kk], wfr[nt][kk], acc[nt], 0, 0, 0);
#pragma unroll
            for (int r = 0; r < 4; ++r) {
                if (w != r) *(float4_*)&redbuf[(w * 64 + lane) * 4] = acc[r];
                __syncthreads();
                if (w == r) {
#pragma unroll
                    for (int wo = 0; wo < 4; ++wo) if (wo != r)
                        acc[r] += *(const float4_*)&redbuf[(wo * 64 + lane) * 4];
                }
                __syncthreads();
            }
            float4_ myy = acc[0];
#pragma unroll
            for (int r = 1; r < 4; ++r) if (w == r) myy = acc[r];
#pragma unroll
            for (int r = 0; r < 4; ++r) {
                int m = cb * 16 + quad * 4 + r;
                out[(size_t)m * 32768 + (size_t)t * 64 + (w * 16 + cl)] = myy[r] + bo_;
            }
            publish(fC, cb, t + 1);
        }
    }
}

extern "C" void kernel_launch(void* const* d_in, const int* in_sizes, int n_in,
                              void* d_out, int out_size, void* d_ws, size_t ws_size,
                              hipStream_t stream) {
    const float* inp  = (const float*)d_in[0];
    const float* Wih1 = (const float*)d_in[1];
    const float* Whh1 = (const float*)d_in[2];
    const float* bih1 = (const float*)d_in[3];
    const float* bhh1 = (const float*)d_in[4];
    const float* Wih2 = (const float*)d_in[5];
    const float* Whh2 = (const float*)d_in[6];
    const float* bih2 = (const float*)d_in[7];
    const float* bhh2 = (const float*)d_in[8];
    const float* Wout = (const float*)d_in[9];
    const float* bout = (const float*)d_in[10];
    char* ws = (char*)d_ws;

    hipMemsetAsync(d_ws, 0, ZERO_BYTES, stream);
    prep_x<<<TSTEPS, 256, 0, stream>>>(inp, ws);
    lstm_persistent<<<NA + NB + NC, 256, 0, stream>>>(Wih1, Whh1, bih1, bhh1,
                                                      Wih2, Whh2, bih2, bhh2,
                                                      Wout, bout, ws, (float*)d_out);
}

// Round 9
// 4270.488 us; speedup vs baseline: 1.9407x; 1.9407x over previous
//
#include <hip/hip_runtime.h>
#include <hip/hip_fp16.h>

typedef _Float16 half8 __attribute__((ext_vector_type(8)));
typedef float    float4_ __attribute__((ext_vector_type(4)));

#define TSTEPS 512
#define NA 64
#define NB 128
#define NC 8
#define FSTRIDE 32                // ints per flag slot = 128 B (own cache line)

// workspace layout (bytes) — IDENTICAL to the proven R1/R4 layout
#define FLA_OFF   0               // 64 flags  x 128 B
#define FLB_OFF   8192            // 128 flags x 128 B
#define FLC_OFF   24576           // 8 flags   x 128 B
#define H1_OFF    32768
#define H1_PHASE  262144          // 1024 cols x 128 batch x 2B, fragment-major
#define H2_OFF    (H1_OFF + 2 * H1_PHASE)
#define X_OFF     (H2_OFF + 2 * H1_PHASE)
#define X_TSTRIDE 16384           // 64 cols x 128 batch x 2B per step
#define ZERO_BYTES X_OFF          // flags + H1 + H2 zeroed each call

// fast activations: v_rcp_f32 + v_exp (R4-proven numerics-neutral)
__device__ __forceinline__ float fastrcp(float x) {
    float r; asm("v_rcp_f32 %0, %1" : "=v"(r) : "v"(x)); return r;
}
__device__ __forceinline__ float sigf(float x)  { return fastrcp(1.0f + __expf(-x)); }
__device__ __forceinline__ float tanh_(float x) { return 1.0f - 2.0f * fastrcp(1.0f + __expf(2.0f * x)); }

__device__ __forceinline__ half8 wfrag_load(const float* Wa, int lda,
                                            const float* Wb, int ldb,
                                            int split, int row, int k0) {
    const float* s = (k0 < split) ? (Wa + (size_t)row * lda + k0)
                                  : (Wb + (size_t)row * ldb + (k0 - split));
    float4_ lo = *(const float4_*)s;
    float4_ hi = *(const float4_*)(s + 4);
    half8 r;
    r[0] = (_Float16)lo[0]; r[1] = (_Float16)lo[1];
    r[2] = (_Float16)lo[2]; r[3] = (_Float16)lo[3];
    r[4] = (_Float16)hi[0]; r[5] = (_Float16)hi[1];
    r[6] = (_Float16)hi[2]; r[7] = (_Float16)hi[3];
    return r;
}

// ---- coherence-point access primitives (R4-proven: sc1 loads, no fences) ----

__device__ __forceinline__ half8 ldg_sc1_16(const void* p) {
    half8 r;
    asm volatile("global_load_dwordx4 %0, %1, off sc1" : "=v"(r) : "v"(p));
    return r;
}

#define VMWAIT8(A) asm volatile("s_waitcnt vmcnt(0)" : \
    "+v"((A)[0]), "+v"((A)[1]), "+v"((A)[2]), "+v"((A)[3]), \
    "+v"((A)[4]), "+v"((A)[5]), "+v"((A)[6]), "+v"((A)[7]) :: "memory")

// counted wait releasing one 2-load group (loads complete in issue order)
#define VMWAIT2_N(G, NS) asm volatile("s_waitcnt vmcnt(" NS ")" : \
    "+v"((G)[0]), "+v"((G)[1]) :: "memory")

// 16B write-through store (sc0 sc1): full-line-coalescable publish store.
__device__ __forceinline__ void stg_coh_16(void* p, float4_ v) {
    asm volatile("global_store_dwordx4 %0, %1, off sc0 sc1" :: "v"(p), "v"(v) : "memory");
}

__device__ __forceinline__ void stg_coh_int(void* p, int v) {
    asm volatile("global_store_dword %0, %1, off sc0 sc1" :: "v"(p), "v"(v) : "memory");
}

__device__ __forceinline__ void publish(int* fbase, int idx, int v) {
    asm volatile("s_waitcnt vmcnt(0)" ::: "memory");
    __syncthreads();
    if (threadIdx.x == 0) stg_coh_int(fbase + idx * FSTRIDE, v);
}

__device__ __forceinline__ int ld_flag(const int* f, int idx) {
    return __hip_atomic_load(f + idx * FSTRIDE, __ATOMIC_RELAXED,
                             __HIP_MEMORY_SCOPE_AGENT);
}

// A-group: need all fA >= t (h1[t-1] ready) and all fB >= t-1 (phase free)
__device__ __forceinline__ void waitA(const int* fA, const int* fB, int t) {
    if (threadIdx.x < 64) {
        const int lane = threadIdx.x;
        for (;;) {
            int a  = ld_flag(fA, lane);
            int b0 = ld_flag(fB, lane);
            int b1 = ld_flag(fB, 64 + lane);
            if (__all((a >= t) && (b0 >= t - 1) && (b1 >= t - 1))) break;
            __builtin_amdgcn_s_sleep(1);
        }
    }
    __syncthreads();
}

// B-group: fA >= t+1 (h1[t]), fB >= t (h2[t-1]), fC >= t-1 (phase free)
__device__ __forceinline__ void waitB(const int* fA, const int* fB, const int* fC, int t) {
    if (threadIdx.x < 64) {
        const int lane = threadIdx.x;
        for (;;) {
            int a  = ld_flag(fA, lane);
            int b0 = ld_flag(fB, lane);
            int b1 = ld_flag(fB, 64 + lane);
            int c  = ld_flag(fC, lane & 7);
            if (__all((a >= t + 1) && (b0 >= t) && (b1 >= t) && (c >= t - 1))) break;
            __builtin_amdgcn_s_sleep(1);
        }
    }
    __syncthreads();
}

// C-group: fB >= t+1 (h2[t] ready)
__device__ __forceinline__ void waitC(const int* fB, int t) {
    if (threadIdx.x < 64) {
        const int lane = threadIdx.x;
        for (;;) {
            int b0 = ld_flag(fB, lane);
            int b1 = ld_flag(fB, 64 + lane);
            if (__all((b0 >= t + 1) && (b1 >= t + 1))) break;
            __builtin_amdgcn_s_sleep(1);
        }
    }
    __syncthreads();
}

// staging-image chunk swizzle (R3/R4-proven: conflict-free, bijective)
__device__ __forceinline__ int swz(int u) {
    return u ^ (((u >> 3) ^ (u >> 7)) & 7);
}

// Convert input [128 b][512 t][64 i] fp32 -> fragment-major fp16 X[t][kt][quad][b][j]
extern "C" __global__ void prep_x(const float* __restrict__ in, char* __restrict__ ws) {
    const int t = blockIdx.x;
    char* X = ws + X_OFF + (size_t)t * X_TSTRIDE;
    for (int idx = threadIdx.x; idx < 8192; idx += 256) {
        int kt = idx >> 12, rem = idx & 4095;
        int quad = rem >> 10, rem2 = rem & 1023;
        int b = rem2 >> 3, j = rem2 & 7;
        int i = kt * 32 + quad * 8 + j;
        float v = in[(size_t)b * 32768 + (size_t)t * 64 + i];
        *(_Float16*)(X + (size_t)idx * 2) = (_Float16)v;
    }
}

extern "C" __global__ __launch_bounds__(256, 1)
void lstm_persistent(const float* __restrict__ Wih1, const float* __restrict__ Whh1,
                     const float* __restrict__ bih1, const float* __restrict__ bhh1,
                     const float* __restrict__ Wih2, const float* __restrict__ Whh2,
                     const float* __restrict__ bih2, const float* __restrict__ bhh2,
                     const float* __restrict__ Wout, const float* __restrict__ bout,
                     char* __restrict__ ws, float* __restrict__ out) {
    const int tid = threadIdx.x;
    const int w = tid >> 6, lane = tid & 63;
    const int quad = lane >> 4, cl = lane & 15;
    const int laneoff = quad * 2048 + cl * 16;
    int* fA = (int*)(ws + FLA_OFF);
    int* fB = (int*)(ws + FLB_OFF);
    int* fC = (int*)(ws + FLC_OFF);
    char* H1 = ws + H1_OFF;
    char* H2 = ws + H2_OFF;
    char* X  = ws + X_OFF;
    const int blk = blockIdx.x;
    // A: weights 136K @0 + stg 4K @139264.  B: weights 128K @0 + stg @131072.
    // C: red 4K @0.  (R5 proved >=156K static LDS loads fine.)
    __shared__ __align__(16) char smem[143360];

    if (blk < NA) {
        // ---------- layer-1 (M-split): h1 cols [c0,c0+16), K = 1088 (34 k-tiles).
        // Waves split BATCH: wave w owns batch-groups 2w, 2w+1. Weights in LDS.
        // No cross-wave reduction.
        char* wlds = smem;
        unsigned short* stga = (unsigned short*)(smem + 139264);
        const int c0 = blk * 16;
        // preload all 34x4 weight fragments (1 KB each) once
        for (int f = tid; f < 8704; f += 256) {
            int kk = f >> 8, rem = f & 255, nt = rem >> 6, ln = rem & 63;
            int row = nt * 1024 + c0 + (ln & 15);
            int k0 = kk * 32 + (ln >> 4) * 8;
            *(half8*)(wlds + (size_t)f * 16) = wfrag_load(Wih1, 64, Whh1, 1024, 64, row, k0);
        }
        __syncthreads();
        float ba[4];
#pragma unroll
        for (int g = 0; g < 4; ++g) ba[g] = bih1[g * 1024 + c0 + cl] + bhh1[g * 1024 + c0 + cl];
        float cst[2][4];
#pragma unroll
        for (int mi = 0; mi < 2; ++mi)
#pragma unroll
            for (int r = 0; r < 4; ++r) cst[mi][r] = 0.0f;
        const int mtb0 = (2 * w) * 256, mtb1 = (2 * w + 1) * 256;

        for (int t = 0; t < TSTEPS; ++t) {
            waitA(fA, fB, t);

            const char* xb  = X + (size_t)t * X_TSTRIDE;
            const char* h1r = H1 + (((t & 1) ^ 1) ? H1_PHASE : 0);
            char*       h1w = H1 + ((t & 1) ? H1_PHASE : 0);

            // ring-10 prefetch (20 outstanding), 2 loads per k-tile.
            // NOTE (R8 NaN fix): reload of slot cur is issued AFTER the MFMAs
            // consume it — ring size == prefetch distance, so kn%10 == cur.
            half8 af[10][2];
#pragma unroll
            for (int p = 0; p < 10; ++p) {
                const char* bp = (p < 2) ? (xb + p * 8192) : (h1r + (p - 2) * 8192);
                af[p][0] = ldg_sc1_16(bp + laneoff + mtb0);
                af[p][1] = ldg_sc1_16(bp + laneoff + mtb1);
            }
            float4_ acc[2][4];
#pragma unroll
            for (int mi = 0; mi < 2; ++mi)
#pragma unroll
                for (int nt = 0; nt < 4; ++nt) acc[mi][nt] = (float4_){0.f, 0.f, 0.f, 0.f};
#pragma unroll
            for (int kk = 0; kk < 34; ++kk) {
                const int cur = kk % 10;
                if (kk <= 24)      { VMWAIT2_N(af[cur], "18"); }
                else if (kk == 25) { VMWAIT2_N(af[cur], "16"); }
                else if (kk == 26) { VMWAIT2_N(af[cur], "14"); }
                else if (kk == 27) { VMWAIT2_N(af[cur], "12"); }
                else if (kk == 28) { VMWAIT2_N(af[cur], "10"); }
                else if (kk == 29) { VMWAIT2_N(af[cur], "8");  }
                else if (kk == 30) { VMWAIT2_N(af[cur], "6");  }
                else if (kk == 31) { VMWAIT2_N(af[cur], "4");  }
                else if (kk == 32) { VMWAIT2_N(af[cur], "2");  }
                else               { VMWAIT2_N(af[cur], "0");  }
                half8 wl0 = *(const half8*)(wlds + (size_t)((kk * 4 + 0) * 64 + lane) * 16);
                half8 wl1 = *(const half8*)(wlds + (size_t)((kk * 4 + 1) * 64 + lane) * 16);
                half8 wl2 = *(const half8*)(wlds + (size_t)((kk * 4 + 2) * 64 + lane) * 16);
                half8 wl3 = *(const half8*)(wlds + (size_t)((kk * 4 + 3) * 64 + lane) * 16);
                acc[0][0] = __builtin_amdgcn_mfma_f32_16x16x32_f16(af[cur][0], wl0, acc[0][0], 0, 0, 0);
                acc[0][1] = __builtin_amdgcn_mfma_f32_16x16x32_f16(af[cur][0], wl1, acc[0][1], 0, 0, 0);
                acc[0][2] = __builtin_amdgcn_mfma_f32_16x16x32_f16(af[cur][0], wl2, acc[0][2], 0, 0, 0);
                acc[0][3] = __builtin_amdgcn_mfma_f32_16x16x32_f16(af[cur][0], wl3, acc[0][3], 0, 0, 0);
                acc[1][0] = __builtin_amdgcn_mfma_f32_16x16x32_f16(af[cur][1], wl0, acc[1][0], 0, 0, 0);
                acc[1][1] = __builtin_amdgcn_mfma_f32_16x16x32_f16(af[cur][1], wl1, acc[1][1], 0, 0, 0);
                acc[1][2] = __builtin_amdgcn_mfma_f32_16x16x32_f16(af[cur][1], wl2, acc[1][2], 0, 0, 0);
                acc[1][3] = __builtin_amdgcn_mfma_f32_16x16x32_f16(af[cur][1], wl3, acc[1][3], 0, 0, 0);
                if (kk + 10 < 34) {
                    const int kn = kk + 10;
                    const char* bn = (kn < 2) ? (xb + kn * 8192) : (h1r + (kn - 2) * 8192);
                    af[cur][0] = ldg_sc1_16(bn + laneoff + mtb0);
                    af[cur][1] = ldg_sc1_16(bn + laneoff + mtb1);
                }
            }
            // nonlinearity -> swizzled staging image (accumulators are complete;
            // wave w owns batch-groups 2w+mi -> same m mapping as R4)
#pragma unroll
            for (int mi = 0; mi < 2; ++mi) {
#pragma unroll
                for (int r = 0; r < 4; ++r) {
                    float iv = acc[mi][0][r] + ba[0];
                    float fv = acc[mi][1][r] + ba[1];
                    float gv = acc[mi][2][r] + ba[2];
                    float ov = acc[mi][3][r] + ba[3];
                    float c = sigf(fv) * cst[mi][r] + sigf(iv) * tanh_(gv);
                    float h = sigf(ov) * tanh_(c);
                    cst[mi][r] = c;
                    int m = (2 * w + mi) * 16 + quad * 4 + r;
                    int u = ((cl >> 3) << 7) + m;
                    union { _Float16 hh; unsigned short us; } uu;
                    uu.hh = (_Float16)h;
                    stga[swz(u) * 8 + (cl & 7)] = uu.us;
                }
            }
            __syncthreads();
            // coalesced publish: one 16B full-line-combinable store per thread
            {
                const int g = tid >> 7, b = tid & 127;
                int u = (g << 7) + b;
                float4_ v = *(const float4_*)(stga + swz(u) * 8);
                char* dst = h1w + ((c0 >> 5) << 13) + ((((c0 >> 3) + g) & 3) << 11) + (b << 4);
                stg_coh_16(dst, v);
            }
            publish(fA, blk, t + 1);
        }
    } else if (blk < NA + NB) {
        // ---------- layer-2 (M-split): h2 cols [c0,c0+8), K = 2048 (64 k-tiles).
        // Waves split BATCH: wave w owns batch-groups 2w, 2w+1. Weights in LDS
        // (packed rows: pr0 = i/f gates, pr1 = g/o gates, hi/lo lane trick).
        char* wldsB = smem;
        unsigned short* stgb = (unsigned short*)(smem + 131072);
        const int bb = blk - NA;
        const int c0 = bb * 8;
        for (int f = tid; f < 8192; f += 256) {
            int kk = f >> 7, rem = f & 127, pr = rem >> 6, ln = rem & 63;
            int cl_ = ln & 15;
            int colB_ = c0 + (cl_ & 7);
            int row = (pr == 0) ? ((cl_ < 8) ? colB_ : (1024 + colB_))
                                : ((cl_ < 8) ? (2048 + colB_) : (3072 + colB_));
            int k0 = kk * 32 + (ln >> 4) * 8;
            *(half8*)(wldsB + (size_t)f * 16) = wfrag_load(Wih2, 1024, Whh2, 1024, 1024, row, k0);
        }
        __syncthreads();
        const int colB = c0 + (cl & 7);
        const float bi = bih2[colB] + bhh2[colB];
        const float bf = bih2[1024 + colB] + bhh2[1024 + colB];
        const float bg = bih2[2048 + colB] + bhh2[2048 + colB];
        const float bo = bih2[3072 + colB] + bhh2[3072 + colB];
        float cst[2][4];
#pragma unroll
        for (int mi = 0; mi < 2; ++mi)
#pragma unroll
            for (int r = 0; r < 4; ++r) cst[mi][r] = 0.0f;
        const bool lolane = (cl & 8) == 0;
        const int mtb0 = (2 * w) * 256, mtb1 = (2 * w + 1) * 256;

        for (int t = 0; t < TSTEPS; ++t) {
            waitB(fA, fB, fC, t);

            const char* h1c = H1 + ((t & 1) ? H1_PHASE : 0);
            const char* h2r = H2 + (((t & 1) ^ 1) ? H1_PHASE : 0);
            char*       h2w = H2 + ((t & 1) ? H1_PHASE : 0);

            // ring-12 prefetch (24 outstanding), 2 loads per k-tile.
            // Same R8 NaN fix: reload issued AFTER MFMAs consume slot cur.
            half8 af[12][2];
#pragma unroll
            for (int p = 0; p < 12; ++p) {
                const char* bp = h1c + p * 8192;      // p < 32 always here
                af[p][0] = ldg_sc1_16(bp + laneoff + mtb0);
                af[p][1] = ldg_sc1_16(bp + laneoff + mtb1);
            }
            float4_ acc[2][2];
#pragma unroll
            for (int mi = 0; mi < 2; ++mi) {
                acc[mi][0] = (float4_){0.f, 0.f, 0.f, 0.f};
                acc[mi][1] = (float4_){0.f, 0.f, 0.f, 0.f};
            }
#pragma unroll
            for (int kk = 0; kk < 64; ++kk) {
                const int cur = kk % 12;
                if (kk <= 52)      { VMWAIT2_N(af[cur], "22"); }
                else if (kk == 53) { VMWAIT2_N(af[cur], "20"); }
                else if (kk == 54) { VMWAIT2_N(af[cur], "18"); }
                else if (kk == 55) { VMWAIT2_N(af[cur], "16"); }
                else if (kk == 56) { VMWAIT2_N(af[cur], "14"); }
                else if (kk == 57) { VMWAIT2_N(af[cur], "12"); }
                else if (kk == 58) { VMWAIT2_N(af[cur], "10"); }
                else if (kk == 59) { VMWAIT2_N(af[cur], "8");  }
                else if (kk == 60) { VMWAIT2_N(af[cur], "6");  }
                else if (kk == 61) { VMWAIT2_N(af[cur], "4");  }
                else if (kk == 62) { VMWAIT2_N(af[cur], "2");  }
                else               { VMWAIT2_N(af[cur], "0");  }
                half8 wl0 = *(const half8*)(wldsB + (size_t)((kk * 2 + 0) * 64 + lane) * 16);
                half8 wl1 = *(const half8*)(wldsB + (size_t)((kk * 2 + 1) * 64 + lane) * 16);
                acc[0][0] = __builtin_amdgcn_mfma_f32_16x16x32_f16(af[cur][0], wl0, acc[0][0], 0, 0, 0);
                acc[0][1] = __builtin_amdgcn_mfma_f32_16x16x32_f16(af[cur][0], wl1, acc[0][1], 0, 0, 0);
                acc[1][0] = __builtin_amdgcn_mfma_f32_16x16x32_f16(af[cur][1], wl0, acc[1][0], 0, 0, 0);
                acc[1][1] = __builtin_amdgcn_mfma_f32_16x16x32_f16(af[cur][1], wl1, acc[1][1], 0, 0, 0);
                if (kk + 12 < 64) {
                    const int kn = kk + 12;
                    const char* bn = (kn < 32) ? (h1c + kn * 8192) : (h2r + (kn - 32) * 8192);
                    af[cur][0] = ldg_sc1_16(bn + laneoff + mtb0);
                    af[cur][1] = ldg_sc1_16(bn + laneoff + mtb1);
                }
            }
            // epilogue (accumulators complete; hi/lo lane exchange as R4)
#pragma unroll
            for (int mi = 0; mi < 2; ++mi) {
#pragma unroll
                for (int r = 0; r < 4; ++r) {
                    float d0 = acc[mi][0][r], d1 = acc[mi][1][r];
                    float s0 = __shfl_xor(d0, 8, 64);
                    float s1 = __shfl_xor(d1, 8, 64);
                    float iv = (lolane ? d0 : s0) + bi;
                    float fv = (lolane ? s0 : d0) + bf;
                    float gv = (lolane ? d1 : s1) + bg;
                    float ov = (lolane ? s1 : d1) + bo;
                    float c = sigf(fv) * cst[mi][r] + sigf(iv) * tanh_(gv);
                    float h = sigf(ov) * tanh_(c);
                    cst[mi][r] = c;
                    if (lolane) {
                        int m = (2 * w + mi) * 16 + quad * 4 + r;
                        union { _Float16 hh; unsigned short us; } uu;
                        uu.hh = (_Float16)h;
                        stgb[swz(m) * 8 + (cl & 7)] = uu.us;
                    }
                }
            }
            __syncthreads();
            if (tid < 128) {
                const int b = tid;
                float4_ v = *(const float4_*)(stgb + swz(b) * 8);
                char* dst = h2w + ((c0 >> 5) << 13) + (((c0 >> 3) & 3) << 11) + (b << 4);
                stg_coh_16(dst, v);
            }
            publish(fB, bb, t + 1);
        }
    } else {
        // ---------- output: batch tile cb, y = h2 @ Wout^T + bout, K = 1024
        float* redc = (float*)smem;
        const int cb = blk - NA - NB;
        const int kbase = w * 8;
        half8 wfr[4][8];
#pragma unroll
        for (int nt = 0; nt < 4; ++nt) {
            int row = nt * 16 + cl;
#pragma unroll
            for (int kk = 0; kk < 8; ++kk)
                wfr[nt][kk] = wfrag_load(Wout, 1024, Wout, 1024, 1 << 30, row, (kbase + kk) * 32 + quad * 8);
        }
        const float bo_ = bout[w * 16 + cl];

        for (int t = 0; t < TSTEPS; ++t) {
            waitC(fB, t);
            const char* h2c = H2 + ((t & 1) ? H1_PHASE : 0);
            float4_ acc[4];
#pragma unroll
            for (int nt = 0; nt < 4; ++nt) acc[nt] = (float4_){0.f, 0.f, 0.f, 0.f};
            half8 af[8];
#pragma unroll
            for (int kk = 0; kk < 8; ++kk)
                af[kk] = ldg_sc1_16(h2c + (kbase + kk) * 8192 + laneoff + cb * 256);
            VMWAIT8(af);
#pragma unroll
            for (int kk = 0; kk < 8; ++kk)
#pragma unroll
                for (int nt = 0; nt < 4; ++nt)
                    acc[nt] = __builtin_amdgcn_mfma_f32_16x16x32_f16(af[kk], wfr[nt][kk], acc[nt], 0, 0, 0);
#pragma unroll
            for (int r = 0; r < 4; ++r) {
                if (w != r) *(float4_*)&redc[(w * 64 + lane) * 4] = acc[r];
                __syncthreads();
                if (w == r) {
#pragma unroll
                    for (int wo = 0; wo < 4; ++wo) if (wo != r)
                        acc[r] += *(const float4_*)&redc[(wo * 64 + lane) * 4];
                }
                __syncthreads();
            }
            float4_ myy = acc[0];
#pragma unroll
            for (int r = 1; r < 4; ++r) if (w == r) myy = acc[r];
#pragma unroll
            for (int r = 0; r < 4; ++r) {
                int m = cb * 16 + quad * 4 + r;
                out[(size_t)m * 32768 + (size_t)t * 64 + (w * 16 + cl)] = myy[r] + bo_;
            }
            publish(fC, cb, t + 1);
        }
    }
}

extern "C" void kernel_launch(void* const* d_in, const int* in_sizes, int n_in,
                              void* d_out, int out_size, void* d_ws, size_t ws_size,
                              hipStream_t stream) {
    const float* inp  = (const float*)d_in[0];
    const float* Wih1 = (const float*)d_in[1];
    const float* Whh1 = (const float*)d_in[2];
    const float* bih1 = (const float*)d_in[3];
    const float* bhh1 = (const float*)d_in[4];
    const float* Wih2 = (const float*)d_in[5];
    const float* Whh2 = (const float*)d_in[6];
    const float* bih2 = (const float*)d_in[7];
    const float* bhh2 = (const float*)d_in[8];
    const float* Wout = (const float*)d_in[9];
    const float* bout = (const float*)d_in[10];
    char* ws = (char*)d_ws;

    hipMemsetAsync(d_ws, 0, ZERO_BYTES, stream);
    prep_x<<<TSTEPS, 256, 0, stream>>>(inp, ws);
    lstm_persistent<<<NA + NB + NC, 256, 0, stream>>>(Wih1, Whh1, bih1, bhh1,
                                                      Wih2, Whh2, bih2, bhh2,
                                                      Wout, bout, ws, (float*)d_out);
}